// Round 15
// baseline (489.104 us; speedup 1.0000x reference)
//
#include <hip/hip_runtime.h>
#include <math.h>

#define NB 64
#define NQ 300
#define NP 6
#define ND 256
#define NF 512
#define NCL 396
#define NT 10
#define POOL_ROWS 65536

typedef float f4 __attribute__((ext_vector_type(4)));

__device__ __forceinline__ float dot4(f4 a, f4 b) {
    return a.x * b.x + a.y * b.y + a.z * b.z + a.w * b.w;
}
__device__ __forceinline__ float wred(float s) {
    #pragma unroll
    for (int o = 32; o; o >>= 1) s += __shfl_down(s, o, 64);
    return s;
}

// ---------------------------------------------------------------------------
// K1: blocks 0..63        -> cls masked-mean pool + key-padding bias
//     blocks 64..64+65535 -> feat global-average-pool rows (plain f4 loads)
// ---------------------------------------------------------------------------
__global__ __launch_bounds__(256) void pool_cls_kernel(
    const float* __restrict__ pred, const float* __restrict__ hs,
    const float* __restrict__ f0, const float* __restrict__ f1,
    const float* __restrict__ f2, const float* __restrict__ f3,
    float* __restrict__ pooled, float* __restrict__ tokG,
    float* __restrict__ biasW)
{
    const int bid = blockIdx.x;
    const int tid = threadIdx.x;
    __shared__ float shm[1824];

    if (bid < NB) {
        const int b = bid;
        float* maskL = shm;
        float* countsL = shm + 1800;
        for (int i = tid; i < NQ * NP; i += 256) {
            float x = pred[(size_t)b * NQ * NP + i];
            float sg = 1.f / (1.f + expf(-x));
            maskL[i] = (sg > 0.3f) ? 1.f : 0.f;
        }
        __syncthreads();
        if (tid < NP) {
            float c = 0.f;
            for (int q = 0; q < NQ; q++) c += maskL[q * NP + tid];
            countsL[tid] = c;
        }
        __syncthreads();
        float acc[NP] = {0.f, 0.f, 0.f, 0.f, 0.f, 0.f};
        const float* hsb = hs + (size_t)b * NQ * ND + tid;
        for (int q = 0; q < NQ; q++) {
            float h = hsb[(size_t)q * ND];
            #pragma unroll
            for (int p = 0; p < NP; p++) acc[p] += maskL[q * NP + p] * h;
        }
        bool anyv = false;
        #pragma unroll
        for (int p = 0; p < NP; p++) anyv = anyv || (countsL[p] > 0.f);
        #pragma unroll
        for (int p = 0; p < NP; p++) {
            float cm = acc[p] / fmaxf(countsL[p], 1.f);
            if (p == 0 && !anyv) cm = hs[(size_t)b * NQ * ND + tid];
            tokG[(size_t)b * 1536 + p * ND + tid] = cm;
        }
        if (tid < 16) {
            float bv = 0.f;
            if (tid < NP) {
                bool v = countsL[tid] > 0.f;
                if (tid == 0 && !anyv) v = true;
                bv = v ? 0.f : -1e30f;
            }
            biasW[b * 16 + tid] = bv;
        }
        return;
    }

    const int row = bid - NB;
    const int scale = row >> 14;
    const int rr = row & 16383;
    const int b = rr >> 8;
    const int d = rr & 255;
    const float* src;
    int n;
    switch (scale) {
        case 0: src = f0; n = 96 * 96; break;
        case 1: src = f1; n = 48 * 48; break;
        case 2: src = f2; n = 24 * 24; break;
        default: src = f3; n = 12 * 12; break;
    }
    const f4* p4 = reinterpret_cast<const f4*>(src + ((size_t)b * ND + d) * (size_t)n);
    int n4 = n >> 2;
    float s = 0.f;
    for (int i = tid; i < n4; i += 256) {
        f4 v = p4[i];
        s += v.x + v.y + v.z + v.w;
    }
    s = wred(s);
    int wid = tid >> 6, lane = tid & 63;
    if (lane == 0) shm[wid] = s;
    __syncthreads();
    if (tid == 0) {
        float t = shm[0] + shm[1] + shm[2] + shm[3];
        pooled[((size_t)b * 4 + scale) * ND + d] = t / (float)n;
    }
}

// ---------------------------------------------------------------------------
// K2: fused per-batch transformer, fp32, register-tiled GEMMs.
// 64 blocks x 512 threads. Thread owns (row-half x CT columns): each
// activation LDS read feeds CT dot4s; all waves active in every heavy phase.
// ---------------------------------------------------------------------------
__global__ __launch_bounds__(512) void xform_kernel(
    const float* __restrict__ pooled, const float* __restrict__ tokG,
    const float* __restrict__ biasW,
    const float* __restrict__ ipw, const float* __restrict__ ipb,
    const float* __restrict__ inw, const float* __restrict__ inb,
    const float* __restrict__ ow, const float* __restrict__ ob,
    const float* __restrict__ l1w, const float* __restrict__ l1b,
    const float* __restrict__ l2w, const float* __restrict__ l2b,
    const float* __restrict__ n1w, const float* __restrict__ n1b,
    const float* __restrict__ n2w, const float* __restrict__ n2b,
    const float* __restrict__ c1w, const float* __restrict__ c1b,
    const float* __restrict__ c2w, const float* __restrict__ c2b,
    float* __restrict__ out)
{
    const int b = blockIdx.x;
    const int tid = threadIdx.x;
    const int lane = tid & 63;
    const int wv = tid >> 6;

    __shared__ __align__(16) float xs[2560];     // current x
    __shared__ __align__(16) float qkvS[7680];   // qkv / FF2 partials
    __shared__ __align__(16) float xr[2560];     // ao / resid / ct
    __shared__ __align__(16) float h1[5120];     // pld / op partials / ff hidden / cls h
    __shared__ float sc[800];
    __shared__ float stats[32];
    __shared__ float biasK[16];

    const f4* xs4 = reinterpret_cast<const f4*>(xs);
    const f4* xr4 = reinterpret_cast<const f4*>(xr);
    const f4* h14 = reinterpret_cast<const f4*>(h1);

    // ---------------- stage ----------------
    for (int i = tid; i < 1536; i += 512) xs[i] = tokG[(size_t)b * 1536 + i];
    for (int i = tid; i < 1024; i += 512) h1[i] = pooled[(size_t)b * 1024 + i];
    if (tid < 16) biasK[tid] = biasW[b * 16 + tid];
    __syncthreads();

    // ---- img tokens: 1024 outputs, 2/thread ----
    for (int idx = tid; idx < 1024; idx += 512) {
        int i = idx >> 8, c = idx & 255;
        const f4* w4 = reinterpret_cast<const f4*>(ipw + ((size_t)i * ND + c) * ND);
        float acc = 0.f;
        #pragma unroll 4
        for (int k4 = 0; k4 < 64; k4++) acc += dot4(w4[k4], h14[i * 64 + k4]);
        xs[(6 + i) * ND + c] = acc + ipb[i * ND + c];
    }
    __syncthreads();

    for (int l = 0; l < 2; l++) {
        // ---- (a) QKV: CT=3 (c,+256,+512), RH=2 — 512 thr, no K-split ----
        {
            const int c = tid & 255, r0 = (tid >> 8) * 5;
            const f4* w0 = reinterpret_cast<const f4*>(inw + ((size_t)l * 768 + c) * ND);
            const f4* w1 = reinterpret_cast<const f4*>(inw + ((size_t)l * 768 + c + 256) * ND);
            const f4* w2 = reinterpret_cast<const f4*>(inw + ((size_t)l * 768 + c + 512) * ND);
            float a0[5], a1[5], a2[5];
            #pragma unroll
            for (int rr = 0; rr < 5; rr++) { a0[rr] = 0.f; a1[rr] = 0.f; a2[rr] = 0.f; }
            #pragma unroll 4
            for (int k4 = 0; k4 < 64; k4++) {
                f4 wa = w0[k4], wb = w1[k4], wc = w2[k4];
                #pragma unroll
                for (int rr = 0; rr < 5; rr++) {
                    f4 xv = xs4[(r0 + rr) * 64 + k4];
                    a0[rr] += dot4(wa, xv);
                    a1[rr] += dot4(wb, xv);
                    a2[rr] += dot4(wc, xv);
                }
            }
            float b0 = inb[l * 768 + c], b1 = inb[l * 768 + c + 256], b2 = inb[l * 768 + c + 512];
            #pragma unroll
            for (int rr = 0; rr < 5; rr++) {
                qkvS[(r0 + rr) * 768 + c] = a0[rr] + b0;
                qkvS[(r0 + rr) * 768 + c + 256] = a1[rr] + b1;
                qkvS[(r0 + rr) * 768 + c + 512] = a2[rr] + b2;
            }
        }
        __syncthreads();

        // ---- (b) scores + bias ----
        for (int t = tid; t < 800; t += 512) {
            int h = t / 100, rem = t - 100 * h;
            int qr = rem / 10, kr = rem - 10 * qr;
            const float* qp = &qkvS[qr * 768 + h * 32];
            const float* kp = &qkvS[kr * 768 + 256 + h * 32];
            float s = 0.f;
            #pragma unroll
            for (int dh = 0; dh < 32; dh++) s += qp[dh] * kp[dh];
            sc[t] = s * 0.17677669529663687f + biasK[kr];
        }
        __syncthreads();

        // ---- (c) softmax ----
        if (tid < 80) {
            float* row = &sc[tid * 10];
            float m = row[0];
            #pragma unroll
            for (int k = 1; k < 10; k++) m = fmaxf(m, row[k]);
            float ss = 0.f;
            #pragma unroll
            for (int k = 0; k < 10; k++) { float e = expf(row[k] - m); row[k] = e; ss += e; }
            float inv = 1.f / ss;
            #pragma unroll
            for (int k = 0; k < 10; k++) row[k] *= inv;
        }
        __syncthreads();

        // ---- (d) attn @ V -> xr (ao) ----
        for (int idx = tid; idx < 2560; idx += 512) {
            int r = idx >> 8, col = idx & 255, h = col >> 5;
            float s = 0.f;
            #pragma unroll
            for (int kr = 0; kr < 10; kr++)
                s += sc[h * 100 + r * 10 + kr] * qkvS[kr * 768 + 512 + col];
            xr[idx] = s;
        }
        __syncthreads();

        // ---- (e) out_proj: CT=2 (c,+128), KS=2, RH=2 — 512 thr ----
        {
            const int c = tid & 127, ks = (tid >> 7) & 1, r0 = (tid >> 8) * 5;
            const f4* w0 = reinterpret_cast<const f4*>(ow + ((size_t)l * ND + c) * ND) + ks * 32;
            const f4* w1 = reinterpret_cast<const f4*>(ow + ((size_t)l * ND + c + 128) * ND) + ks * 32;
            float a0[5], a1[5];
            #pragma unroll
            for (int rr = 0; rr < 5; rr++) { a0[rr] = 0.f; a1[rr] = 0.f; }
            #pragma unroll 4
            for (int k4 = 0; k4 < 32; k4++) {
                f4 wa = w0[k4], wb = w1[k4];
                #pragma unroll
                for (int rr = 0; rr < 5; rr++) {
                    f4 av = xr4[(r0 + rr) * 64 + ks * 32 + k4];
                    a0[rr] += dot4(wa, av);
                    a1[rr] += dot4(wb, av);
                }
            }
            __syncthreads();          // all ao reads done before partial writes to h1
            #pragma unroll
            for (int rr = 0; rr < 5; rr++) {
                h1[ks * 2560 + (r0 + rr) * 256 + c] = a0[rr];
                h1[ks * 2560 + (r0 + rr) * 256 + c + 128] = a1[rr];
            }
        }
        __syncthreads();
        for (int i = tid; i < 2560; i += 512)
            xr[i] = xs[i] + h1[i] + h1[2560 + i] + ob[l * ND + (i & 255)];
        __syncthreads();

        // ---- (f) LN1: xr -> xs ----
        for (int r = wv; r < NT; r += 8) {
            float v0 = xr[r * ND + lane], v1 = xr[r * ND + 64 + lane];
            float v2 = xr[r * ND + 128 + lane], v3 = xr[r * ND + 192 + lane];
            float s = wred(v0 + v1 + v2 + v3);
            float q = wred(v0 * v0 + v1 * v1 + v2 * v2 + v3 * v3);
            if (lane == 0) {
                float m = s * (1.f / ND);
                stats[r] = m;
                stats[16 + r] = rsqrtf(fmaxf(q * (1.f / ND) - m * m, 0.f) + 1e-5f);
            }
        }
        __syncthreads();
        for (int i = tid; i < 2560; i += 512) {
            int r = i >> 8, c = i & 255;
            xs[i] = (xr[i] - stats[r]) * stats[16 + r] * n1w[l * ND + c] + n1b[l * ND + c];
        }
        __syncthreads();

        // ---- (g) FF1: CT=4 (c,+128,+256,+384), RH=2 — 256 thr, no K-split ----
        if (tid < 256) {
            const int c = tid & 127, r0 = (tid >> 7) * 5;
            const f4* w0 = reinterpret_cast<const f4*>(l1w + ((size_t)l * NF + c) * ND);
            const f4* w1 = reinterpret_cast<const f4*>(l1w + ((size_t)l * NF + c + 128) * ND);
            const f4* w2 = reinterpret_cast<const f4*>(l1w + ((size_t)l * NF + c + 256) * ND);
            const f4* w3 = reinterpret_cast<const f4*>(l1w + ((size_t)l * NF + c + 384) * ND);
            float a0[5], a1[5], a2[5], a3[5];
            #pragma unroll
            for (int rr = 0; rr < 5; rr++) { a0[rr] = 0.f; a1[rr] = 0.f; a2[rr] = 0.f; a3[rr] = 0.f; }
            #pragma unroll 2
            for (int k4 = 0; k4 < 64; k4++) {
                f4 wa = w0[k4], wb = w1[k4], wc = w2[k4], wd = w3[k4];
                #pragma unroll
                for (int rr = 0; rr < 5; rr++) {
                    f4 xv = xs4[(r0 + rr) * 64 + k4];
                    a0[rr] += dot4(wa, xv);
                    a1[rr] += dot4(wb, xv);
                    a2[rr] += dot4(wc, xv);
                    a3[rr] += dot4(wd, xv);
                }
            }
            float b0 = l1b[l * NF + c], b1 = l1b[l * NF + c + 128];
            float b2 = l1b[l * NF + c + 256], b3 = l1b[l * NF + c + 384];
            __syncthreads();          // h1 (op partials) fully consumed earlier
            #pragma unroll
            for (int rr = 0; rr < 5; rr++) {
                h1[(r0 + rr) * NF + c] = fmaxf(a0[rr] + b0, 0.f);
                h1[(r0 + rr) * NF + c + 128] = fmaxf(a1[rr] + b1, 0.f);
                h1[(r0 + rr) * NF + c + 256] = fmaxf(a2[rr] + b2, 0.f);
                h1[(r0 + rr) * NF + c + 384] = fmaxf(a3[rr] + b3, 0.f);
            }
        } else {
            __syncthreads();
        }
        __syncthreads();

        // ---- (h) FF2: CT=2 (c,+128), KS=2, RH=2 — 512 thr ----
        {
            const int c = tid & 127, ks = (tid >> 7) & 1, r0 = (tid >> 8) * 5;
            const f4* w0 = reinterpret_cast<const f4*>(l2w + ((size_t)l * ND + c) * NF) + ks * 64;
            const f4* w1 = reinterpret_cast<const f4*>(l2w + ((size_t)l * ND + c + 128) * NF) + ks * 64;
            float a0[5], a1[5];
            #pragma unroll
            for (int rr = 0; rr < 5; rr++) { a0[rr] = 0.f; a1[rr] = 0.f; }
            #pragma unroll 4
            for (int k4 = 0; k4 < 64; k4++) {
                f4 wa = w0[k4], wb = w1[k4];
                #pragma unroll
                for (int rr = 0; rr < 5; rr++) {
                    f4 hv = h14[(r0 + rr) * 128 + ks * 64 + k4];
                    a0[rr] += dot4(wa, hv);
                    a1[rr] += dot4(wb, hv);
                }
            }
            __syncthreads();          // h1 reads done; qkvS dead since AV
            #pragma unroll
            for (int rr = 0; rr < 5; rr++) {
                qkvS[ks * 2560 + (r0 + rr) * 256 + c] = a0[rr];
                qkvS[ks * 2560 + (r0 + rr) * 256 + c + 128] = a1[rr];
            }
        }
        __syncthreads();
        for (int i = tid; i < 2560; i += 512)
            xr[i] = xs[i] + qkvS[i] + qkvS[2560 + i] + l2b[l * ND + (i & 255)];
        __syncthreads();

        // ---- (i) LN2: xr -> xs ----
        for (int r = wv; r < NT; r += 8) {
            float v0 = xr[r * ND + lane], v1 = xr[r * ND + 64 + lane];
            float v2 = xr[r * ND + 128 + lane], v3 = xr[r * ND + 192 + lane];
            float s = wred(v0 + v1 + v2 + v3);
            float q = wred(v0 * v0 + v1 * v1 + v2 * v2 + v3 * v3);
            if (lane == 0) {
                float m = s * (1.f / ND);
                stats[r] = m;
                stats[16 + r] = rsqrtf(fmaxf(q * (1.f / ND) - m * m, 0.f) + 1e-5f);
            }
        }
        __syncthreads();
        for (int i = tid; i < 2560; i += 512) {
            int r = i >> 8, c = i & 255;
            xs[i] = (xr[i] - stats[r]) * stats[16 + r] * n2w[l * ND + c] + n2b[l * ND + c];
        }
        __syncthreads();
    }

    // ---------------- epilogue ----------------
    if (tid < ND) {
        float len = 0.f, s = 0.f;
        #pragma unroll
        for (int r = 0; r < NT; r++) {
            float v = (biasK[r] == 0.f) ? 1.f : 0.f;
            len += v;
            s += v * xs[r * ND + tid];
        }
        xr[tid] = s / fmaxf(len, 1.f);
    }
    __syncthreads();

    // cls1: 512 outputs, thread = col
    {
        const f4* w4 = reinterpret_cast<const f4*>(c1w + (size_t)tid * ND);
        const f4* ct4 = reinterpret_cast<const f4*>(xr);
        float acc = 0.f;
        #pragma unroll 4
        for (int k4 = 0; k4 < 64; k4++) acc += dot4(w4[k4], ct4[k4]);
        float hb = fmaxf(acc + c1b[tid], 0.f);
        __syncthreads();   // h1 dead (FF2 consumed it)
        h1[tid] = hb;
    }
    __syncthreads();

    // cls2: 396 outputs
    if (tid < NCL) {
        const f4* w4 = reinterpret_cast<const f4*>(c2w + (size_t)tid * NF);
        float acc = 0.f;
        #pragma unroll 4
        for (int k4 = 0; k4 < 128; k4++) acc += dot4(w4[k4], h14[k4]);
        out[(size_t)b * NCL + tid] = acc + c2b[tid];
    }
}

// ---------------------------------------------------------------------------
extern "C" void kernel_launch(void* const* d_in, const int* in_sizes, int n_in,
                              void* d_out, int out_size, void* d_ws, size_t ws_size,
                              hipStream_t stream)
{
    const float* pred = (const float*)d_in[0];
    const float* hs   = (const float*)d_in[1];
    const float* f0   = (const float*)d_in[2];
    const float* f1   = (const float*)d_in[3];
    const float* f2   = (const float*)d_in[4];
    const float* f3   = (const float*)d_in[5];
    const float* ipw  = (const float*)d_in[6];
    const float* ipb  = (const float*)d_in[7];
    const float* inw  = (const float*)d_in[8];
    const float* inb  = (const float*)d_in[9];
    const float* ow   = (const float*)d_in[10];
    const float* ob   = (const float*)d_in[11];
    const float* l1w  = (const float*)d_in[12];
    const float* l1b  = (const float*)d_in[13];
    const float* l2w  = (const float*)d_in[14];
    const float* l2b  = (const float*)d_in[15];
    const float* ln1w = (const float*)d_in[16];
    const float* ln1b = (const float*)d_in[17];
    const float* ln2w = (const float*)d_in[18];
    const float* ln2b = (const float*)d_in[19];
    const float* c1w  = (const float*)d_in[20];
    const float* c1b  = (const float*)d_in[21];
    const float* c2w  = (const float*)d_in[22];
    const float* c2b  = (const float*)d_in[23];

    float* ws = (float*)d_ws;
    float* pooled = ws;                    // 65536
    float* tokG   = pooled + NB * 4 * ND;  // 98304
    float* biasW  = tokG + NB * 1536;      // 1024

    pool_cls_kernel<<<NB + POOL_ROWS, 256, 0, stream>>>(
        pred, hs, f0, f1, f2, f3, pooled, tokG, biasW);
    xform_kernel<<<NB, 512, 0, stream>>>(
        pooled, tokG, biasW, ipw, ipb, inw, inb, ow, ob, l1w, l1b, l2w, l2b,
        ln1w, ln1b, ln2w, ln2b, c1w, c1b, c2w, c2b, (float*)d_out);
}

// Round 17
// 479.404 us; speedup vs baseline: 1.0202x; 1.0202x over previous
//
#include <hip/hip_runtime.h>
#include <hip/hip_fp16.h>
#include <math.h>

#define NB 64
#define NQ 300
#define NP 6
#define ND 256
#define NF 512
#define NCL 396
#define NT 10

// fp16 weight workspace layout (element offsets in halves)
#define IPW_OFF 0
#define INW_OFF 262144
#define OW_OFF  655360
#define L1W_OFF 786432
#define L2W_OFF 1048576
#define C1W_OFF 1310720
#define C2W_OFF 1441792
#define TOTW    1644544
#define CONV_BLOCKS 803
#define POOL_ROWS 65536

typedef float f4 __attribute__((ext_vector_type(4)));

__device__ __forceinline__ float wred(float s) {
    #pragma unroll
    for (int o = 32; o; o >>= 1) s += __shfl_down(s, o, 64);
    return s;
}

__device__ __forceinline__ float dot8h(f4 wv, f4 xlo, f4 xhi) {
    const __half2* hp = reinterpret_cast<const __half2*>(&wv);
    float2 p0 = __half22float2(hp[0]);
    float2 p1 = __half22float2(hp[1]);
    float2 p2 = __half22float2(hp[2]);
    float2 p3 = __half22float2(hp[3]);
    return p0.x * xlo.x + p0.y * xlo.y + p1.x * xlo.z + p1.y * xlo.w
         + p2.x * xhi.x + p2.y * xhi.y + p3.x * xhi.z + p3.y * xhi.w;
}

// 4-sibling spin barrier (device scope; flags zeroed by K1 each call).
__device__ __forceinline__ void qsync(int* flag, int tid) {
    __syncthreads();
    if (tid == 0) {
        __threadfence();
        __hip_atomic_fetch_add(flag, 1, __ATOMIC_ACQ_REL, __HIP_MEMORY_SCOPE_AGENT);
        while (__hip_atomic_load(flag, __ATOMIC_ACQUIRE, __HIP_MEMORY_SCOPE_AGENT) < 4)
            __builtin_amdgcn_s_sleep(2);
    }
    __syncthreads();
}

// ---------------------------------------------------------------------------
// K1: blocks 0..63          -> cls masked-mean pool + bias (+ zero sync flags)
//     blocks 64..64+65535   -> feat pooling (nontemporal loads)
//     rest                  -> f32 -> fp16 weight conversion
// K1 is a pure function of inputs (no cross-block sync) -> double-launch safe.
// ---------------------------------------------------------------------------
__global__ __launch_bounds__(256) void pool_cls_kernel(
    const float* __restrict__ pred, const float* __restrict__ hs,
    const float* __restrict__ f0, const float* __restrict__ f1,
    const float* __restrict__ f2, const float* __restrict__ f3,
    const float* __restrict__ ipw, const float* __restrict__ inw,
    const float* __restrict__ ow, const float* __restrict__ l1w,
    const float* __restrict__ l2w, const float* __restrict__ c1w,
    const float* __restrict__ c2w,
    float* __restrict__ pooled, float* __restrict__ tokG,
    float* __restrict__ biasW, __half* __restrict__ wH,
    int* __restrict__ flagW)
{
    const int bid = blockIdx.x;
    const int tid = threadIdx.x;
    __shared__ float shm[1824];

    if (bid < NB) {
        const int b = bid;
        if (tid < 16) flagW[b * 16 + tid] = 0;
        float* maskL = shm;
        float* countsL = shm + 1800;
        for (int i = tid; i < NQ * NP; i += 256) {
            float x = pred[(size_t)b * NQ * NP + i];
            float sg = 1.f / (1.f + expf(-x));
            maskL[i] = (sg > 0.3f) ? 1.f : 0.f;
        }
        __syncthreads();
        if (tid < NP) {
            float c = 0.f;
            for (int q = 0; q < NQ; q++) c += maskL[q * NP + tid];
            countsL[tid] = c;
        }
        __syncthreads();
        float acc[NP] = {0.f, 0.f, 0.f, 0.f, 0.f, 0.f};
        const float* hsb = hs + (size_t)b * NQ * ND + tid;
        for (int q = 0; q < NQ; q++) {
            float h = hsb[(size_t)q * ND];
            #pragma unroll
            for (int p = 0; p < NP; p++) acc[p] += maskL[q * NP + p] * h;
        }
        bool anyv = false;
        #pragma unroll
        for (int p = 0; p < NP; p++) anyv = anyv || (countsL[p] > 0.f);
        #pragma unroll
        for (int p = 0; p < NP; p++) {
            float cm = acc[p] / fmaxf(countsL[p], 1.f);
            if (p == 0 && !anyv) cm = hs[(size_t)b * NQ * ND + tid];
            tokG[(size_t)b * 2560 + p * ND + tid] = cm;
        }
        if (tid < 16) {
            float bv = 0.f;
            if (tid < NP) {
                bool v = countsL[tid] > 0.f;
                if (tid == 0 && !anyv) v = true;
                bv = v ? 0.f : -1e30f;
            }
            biasW[b * 16 + tid] = bv;
        }
        return;
    }

    if (bid >= NB + POOL_ROWS) {
        const int cid = bid - (NB + POOL_ROWS);
        size_t base = (size_t)cid * 2048 + (size_t)tid * 8;
        const float* src; size_t off;
        if      (base < INW_OFF) { src = ipw; off = IPW_OFF; }
        else if (base < OW_OFF)  { src = inw; off = INW_OFF; }
        else if (base < L1W_OFF) { src = ow;  off = OW_OFF;  }
        else if (base < L2W_OFF) { src = l1w; off = L1W_OFF; }
        else if (base < C1W_OFF) { src = l2w; off = L2W_OFF; }
        else if (base < C2W_OFF) { src = c1w; off = C1W_OFF; }
        else                     { src = c2w; off = C2W_OFF; }
        const f4* s4 = reinterpret_cast<const f4*>(src + (base - off));
        f4 a = s4[0], b2 = s4[1];
        union { __half2 h[4]; f4 v; } u;
        u.h[0] = __floats2half2_rn(a.x, a.y);
        u.h[1] = __floats2half2_rn(a.z, a.w);
        u.h[2] = __floats2half2_rn(b2.x, b2.y);
        u.h[3] = __floats2half2_rn(b2.z, b2.w);
        *reinterpret_cast<f4*>(wH + base) = u.v;
        return;
    }

    const int row = bid - NB;
    const int scale = row >> 14;
    const int rr = row & 16383;
    const int b = rr >> 8;
    const int d = rr & 255;
    const float* src;
    int n;
    switch (scale) {
        case 0: src = f0; n = 96 * 96; break;
        case 1: src = f1; n = 48 * 48; break;
        case 2: src = f2; n = 24 * 24; break;
        default: src = f3; n = 12 * 12; break;
    }
    const f4* p4 = reinterpret_cast<const f4*>(src + ((size_t)b * ND + d) * (size_t)n);
    int n4 = n >> 2;
    float s = 0.f;
    for (int i = tid; i < n4; i += 256) {
        f4 v = __builtin_nontemporal_load(&p4[i]);
        s += v.x + v.y + v.z + v.w;
    }
    s = wred(s);
    int wid = tid >> 6, lane = tid & 63;
    if (lane == 0) shm[wid] = s;
    __syncthreads();
    if (tid == 0) {
        float t = shm[0] + shm[1] + shm[2] + shm[3];
        pooled[((size_t)b * 4 + scale) * ND + d] = t / (float)n;
    }
}

// ---------------------------------------------------------------------------
// K2: column-split transformer (R13, unchanged). 256 blocks x 512 thr.
// ---------------------------------------------------------------------------
__global__ __launch_bounds__(512) void xform_kernel(
    const float* __restrict__ pooled, float* tokG,
    const float* __restrict__ biasW, const __half* __restrict__ wH,
    const float* __restrict__ ipb, const float* __restrict__ inb,
    const float* __restrict__ ob, const float* __restrict__ l1b,
    const float* __restrict__ l2b,
    const float* __restrict__ n1w, const float* __restrict__ n1b,
    const float* __restrict__ n2w, const float* __restrict__ n2b,
    const float* __restrict__ c1b, const float* __restrict__ c2b,
    float* aoW, float* resW, float* h1W, float* hW,
    int* flagW, float* __restrict__ out)
{
    const int b  = blockIdx.x >> 2;
    const int qt = blockIdx.x & 3;
    const int tid = threadIdx.x;
    const int lane = tid & 63;
    const int wv = tid >> 6;
    int* flags = flagW + b * 16;

    __shared__ __align__(16) float xs[2560];
    __shared__ __align__(16) float loc[1920];
    __shared__ __align__(16) float buf[5120];
    __shared__ __align__(16) float part[5120];
    __shared__ float sc[224];
    __shared__ float stats[32];
    __shared__ float biasK[16];

    const f4* xs4 = reinterpret_cast<const f4*>(xs);
    const f4* buf4 = reinterpret_cast<const f4*>(buf);

    for (int i = tid; i < 1536; i += 512) xs[i] = tokG[(size_t)b * 2560 + i];
    for (int i = tid; i < 1024; i += 512) buf[i] = pooled[(size_t)b * 1024 + i];
    if (tid < 16) biasK[tid] = biasW[b * 16 + tid];
    __syncthreads();

    if (tid < 256) {
        const int i = tid >> 6, cl = tid & 63;
        const int c = qt * 64 + cl;
        const f4* w4 = reinterpret_cast<const f4*>(wH + IPW_OFF + ((size_t)(i * 256 + c)) * 256);
        float acc = 0.f;
        #pragma unroll 4
        for (int k8 = 0; k8 < 32; k8++)
            acc += dot8h(w4[k8], buf4[i * 64 + 2 * k8], buf4[i * 64 + 2 * k8 + 1]);
        tokG[(size_t)b * 2560 + (6 + i) * 256 + c] = acc + ipb[i * 256 + c];
    }
    qsync(&flags[0], tid);
    for (int i = tid + 1536; i < 2560; i += 512) xs[i] = tokG[(size_t)b * 2560 + i];
    __syncthreads();

    for (int l = 0; l < 2; l++) {
        if (tid < 384) {
            const int ks = tid / 192, cl = tid % 192;
            const int m = cl >> 6;
            const int gc = m * 256 + qt * 64 + (cl & 63);
            const f4* w4 = reinterpret_cast<const f4*>(wH + INW_OFF + ((size_t)l * 768 + gc) * 256 + ks * 128);
            float acc[NT];
            #pragma unroll
            for (int r = 0; r < NT; r++) acc[r] = 0.f;
            for (int k8 = 0; k8 < 16; k8++) {
                f4 wv4 = w4[k8];
                const int xi = ks * 32 + 2 * k8;
                #pragma unroll
                for (int r = 0; r < NT; r++)
                    acc[r] += dot8h(wv4, xs4[r * 64 + xi], xs4[r * 64 + xi + 1]);
            }
            #pragma unroll
            for (int r = 0; r < NT; r++) part[ks * 1920 + r * 192 + cl] = acc[r];
        }
        __syncthreads();
        for (int i = tid; i < 1920; i += 512) {
            int r = i / 192, cl = i - r * 192;
            int m = cl >> 6, gc = m * 256 + qt * 64 + (cl & 63);
            loc[i] = part[i] + part[1920 + i] + inb[l * 768 + gc];
        }
        __syncthreads();

        if (tid < 200) {
            int hl = tid / 100, rem = tid - 100 * hl;
            int qr = rem / 10, kr = rem - 10 * qr;
            const float* qp = &loc[qr * 192 + hl * 32];
            const float* kp = &loc[kr * 192 + 64 + hl * 32];
            float s = 0.f;
            #pragma unroll
            for (int d = 0; d < 32; d++) s += qp[d] * kp[d];
            sc[tid] = s * 0.17677669529663687f + biasK[kr];
        }
        __syncthreads();
        if (tid < 20) {
            float* row = &sc[tid * 10];
            float m = row[0];
            #pragma unroll
            for (int k = 1; k < 10; k++) m = fmaxf(m, row[k]);
            float ss = 0.f;
            #pragma unroll
            for (int k = 0; k < 10; k++) { float e = expf(row[k] - m); row[k] = e; ss += e; }
            float inv = 1.f / ss;
            #pragma unroll
            for (int k = 0; k < 10; k++) row[k] *= inv;
        }
        __syncthreads();

        for (int idx = tid; idx < 640; idx += 512) {
            int hl = idx / 320, rem = idx - 320 * hl;
            int r = rem >> 5, c = rem & 31;
            float s = 0.f;
            #pragma unroll
            for (int kr = 0; kr < 10; kr++)
                s += sc[hl * 100 + r * 10 + kr] * loc[kr * 192 + 128 + hl * 32 + c];
            aoW[(size_t)b * 2560 + r * 256 + qt * 64 + hl * 32 + c] = s;
        }
        qsync(&flags[1 + l * 4], tid);
        for (int i = tid; i < 2560; i += 512) buf[i] = aoW[(size_t)b * 2560 + i];
        __syncthreads();

        if (tid < 256) {
            const int ks = tid >> 6, cl = tid & 63;
            const int gc = qt * 64 + cl;
            const f4* w4 = reinterpret_cast<const f4*>(wH + OW_OFF + ((size_t)l * 256 + gc) * 256 + ks * 64);
            float acc[NT];
            #pragma unroll
            for (int r = 0; r < NT; r++) acc[r] = 0.f;
            for (int k8 = 0; k8 < 8; k8++) {
                f4 wv4 = w4[k8];
                const int xi = ks * 16 + 2 * k8;
                #pragma unroll
                for (int r = 0; r < NT; r++)
                    acc[r] += dot8h(wv4, buf4[r * 64 + xi], buf4[r * 64 + xi + 1]);
            }
            #pragma unroll
            for (int r = 0; r < NT; r++) part[ks * 640 + r * 64 + cl] = acc[r];
        }
        __syncthreads();
        for (int i = tid; i < 640; i += 512) {
            int r = i >> 6, cl = i & 63, gc = qt * 64 + cl;
            float v = part[i] + part[640 + i] + part[1280 + i] + part[1920 + i]
                    + ob[l * 256 + gc] + xs[r * 256 + gc];
            resW[(size_t)b * 2560 + r * 256 + gc] = v;
        }
        qsync(&flags[2 + l * 4], tid);
        for (int i = tid; i < 2560; i += 512) buf[i] = resW[(size_t)b * 2560 + i];
        __syncthreads();

        for (int r = wv; r < NT; r += 8) {
            float v0 = buf[r * 256 + lane], v1 = buf[r * 256 + 64 + lane];
            float v2 = buf[r * 256 + 128 + lane], v3 = buf[r * 256 + 192 + lane];
            float s = wred(v0 + v1 + v2 + v3);
            float q = wred(v0 * v0 + v1 * v1 + v2 * v2 + v3 * v3);
            if (lane == 0) {
                float m = s * (1.f / 256.f);
                stats[r] = m;
                stats[16 + r] = rsqrtf(fmaxf(q * (1.f / 256.f) - m * m, 0.f) + 1e-5f);
            }
        }
        __syncthreads();
        for (int i = tid; i < 2560; i += 512) {
            int r = i >> 8, c = i & 255;
            xs[i] = (buf[i] - stats[r]) * stats[16 + r] * n1w[l * 256 + c] + n1b[l * 256 + c];
        }
        __syncthreads();

        {
            const int ks = tid >> 7, cl = tid & 127;
            const int gc = qt * 128 + cl;
            const f4* w4 = reinterpret_cast<const f4*>(wH + L1W_OFF + ((size_t)l * 512 + gc) * 256 + ks * 64);
            float acc[NT];
            #pragma unroll
            for (int r = 0; r < NT; r++) acc[r] = 0.f;
            for (int k8 = 0; k8 < 8; k8++) {
                f4 wv4 = w4[k8];
                const int xi = ks * 16 + 2 * k8;
                #pragma unroll
                for (int r = 0; r < NT; r++)
                    acc[r] += dot8h(wv4, xs4[r * 64 + xi], xs4[r * 64 + xi + 1]);
            }
            __syncthreads();
            #pragma unroll
            for (int r = 0; r < NT; r++) buf[ks * 1280 + r * 128 + cl] = acc[r];
        }
        __syncthreads();
        for (int i = tid; i < 1280; i += 512) {
            int r = i >> 7, cl = i & 127, gc = qt * 128 + cl;
            float h = fmaxf(buf[i] + buf[1280 + i] + buf[2560 + i] + buf[3840 + i]
                          + l1b[l * 512 + gc], 0.f);
            h1W[(size_t)b * 5120 + r * 512 + gc] = h;
        }
        qsync(&flags[3 + l * 4], tid);
        for (int i = tid; i < 5120; i += 512) buf[i] = h1W[(size_t)b * 5120 + i];
        __syncthreads();

        {
            const int ks = tid >> 6, cl = tid & 63;
            const int gc = qt * 64 + cl;
            const f4* w4 = reinterpret_cast<const f4*>(wH + L2W_OFF + ((size_t)l * 256 + gc) * 512 + ks * 64);
            float acc[NT];
            #pragma unroll
            for (int r = 0; r < NT; r++) acc[r] = 0.f;
            for (int k8 = 0; k8 < 8; k8++) {
                f4 wv4 = w4[k8];
                const int xi = ks * 16 + 2 * k8;
                #pragma unroll
                for (int r = 0; r < NT; r++)
                    acc[r] += dot8h(wv4, buf4[r * 128 + xi], buf4[r * 128 + xi + 1]);
            }
            #pragma unroll
            for (int r = 0; r < NT; r++) part[ks * 640 + r * 64 + cl] = acc[r];
        }
        __syncthreads();
        for (int i = tid; i < 640; i += 512) {
            int r = i >> 6, cl = i & 63, gc = qt * 64 + cl;
            float v = part[i] + part[640 + i] + part[1280 + i] + part[1920 + i]
                    + part[2560 + i] + part[3200 + i] + part[3840 + i] + part[4480 + i]
                    + l2b[l * 256 + gc] + xs[r * 256 + gc];
            resW[(size_t)b * 2560 + r * 256 + gc] = v;
        }
        qsync(&flags[4 + l * 4], tid);
        for (int i = tid; i < 2560; i += 512) buf[i] = resW[(size_t)b * 2560 + i];
        __syncthreads();

        for (int r = wv; r < NT; r += 8) {
            float v0 = buf[r * 256 + lane], v1 = buf[r * 256 + 64 + lane];
            float v2 = buf[r * 256 + 128 + lane], v3 = buf[r * 256 + 192 + lane];
            float s = wred(v0 + v1 + v2 + v3);
            float q = wred(v0 * v0 + v1 * v1 + v2 * v2 + v3 * v3);
            if (lane == 0) {
                float m = s * (1.f / 256.f);
                stats[r] = m;
                stats[16 + r] = rsqrtf(fmaxf(q * (1.f / 256.f) - m * m, 0.f) + 1e-5f);
            }
        }
        __syncthreads();
        for (int i = tid; i < 2560; i += 512) {
            int r = i >> 8, c = i & 255;
            xs[i] = (buf[i] - stats[r]) * stats[16 + r] * n2w[l * 256 + c] + n2b[l * 256 + c];
        }
        __syncthreads();
    }

    if (tid < 256) {
        float len = 0.f, s = 0.f;
        #pragma unroll
        for (int r = 0; r < NT; r++) {
            float v = (biasK[r] == 0.f) ? 1.f : 0.f;
            len += v;
            s += v * xs[r * 256 + tid];
        }
        buf[tid] = s / fmaxf(len, 1.f);
    }
    __syncthreads();

    if (tid < 256) {
        const int ks = tid >> 7, cl = tid & 127;
        const int gc = qt * 128 + cl;
        const f4* w4 = reinterpret_cast<const f4*>(wH + C1W_OFF + (size_t)gc * 256 + ks * 128);
        float acc = 0.f;
        #pragma unroll 4
        for (int k8 = 0; k8 < 16; k8++)
            acc += dot8h(w4[k8], buf4[ks * 32 + 2 * k8], buf4[ks * 32 + 2 * k8 + 1]);
        part[ks * 128 + cl] = acc;
    }
    __syncthreads();
    if (tid < 128) {
        const int gc = qt * 128 + tid;
        hW[(size_t)b * 512 + gc] = fmaxf(part[tid] + part[128 + tid] + c1b[gc], 0.f);
    }
    qsync(&flags[9], tid);
    for (int i = tid; i < 512; i += 512) buf[i] = hW[(size_t)b * 512 + i];
    __syncthreads();

    if (tid < 99) {
        const int o = qt * 99 + tid;
        const f4* w4 = reinterpret_cast<const f4*>(wH + C2W_OFF + (size_t)o * 512);
        float acc = 0.f;
        #pragma unroll 4
        for (int k8 = 0; k8 < 64; k8++)
            acc += dot8h(w4[k8], buf4[2 * k8], buf4[2 * k8 + 1]);
        out[(size_t)b * NCL + o] = acc + c2b[o];
    }
}

// ---------------------------------------------------------------------------
extern "C" void kernel_launch(void* const* d_in, const int* in_sizes, int n_in,
                              void* d_out, int out_size, void* d_ws, size_t ws_size,
                              hipStream_t stream)
{
    const float* pred = (const float*)d_in[0];
    const float* hs   = (const float*)d_in[1];
    const float* f0   = (const float*)d_in[2];
    const float* f1   = (const float*)d_in[3];
    const float* f2   = (const float*)d_in[4];
    const float* f3   = (const float*)d_in[5];
    const float* ipw  = (const float*)d_in[6];
    const float* ipb  = (const float*)d_in[7];
    const float* inw  = (const float*)d_in[8];
    const float* inb  = (const float*)d_in[9];
    const float* ow   = (const float*)d_in[10];
    const float* ob   = (const float*)d_in[11];
    const float* l1w  = (const float*)d_in[12];
    const float* l1b  = (const float*)d_in[13];
    const float* l2w  = (const float*)d_in[14];
    const float* l2b  = (const float*)d_in[15];
    const float* ln1w = (const float*)d_in[16];
    const float* ln1b = (const float*)d_in[17];
    const float* ln2w = (const float*)d_in[18];
    const float* ln2b = (const float*)d_in[19];
    const float* c1w  = (const float*)d_in[20];
    const float* c1b  = (const float*)d_in[21];
    const float* c2w  = (const float*)d_in[22];
    const float* c2b  = (const float*)d_in[23];

    float* ws = (float*)d_ws;
    float* pooled = ws;
    float* tokG   = pooled + NB * 4 * ND;
    float* biasW  = tokG + NB * 2560;
    __half* wH    = (__half*)(biasW + 1024);
    float* aoW    = (float*)(wH + TOTW);
    float* resW   = aoW + NB * 2560;
    float* h1W    = resW + NB * 2560;
    float* hW     = h1W + NB * 5120;
    int*   flagW  = (int*)(hW + NB * 512);

    // K1 twice (K1 is a pure function of the inputs — no cross-block sync,
    // second run writes identical values; flags re-zeroed before xform).
    // Decomposition: K1 = (this round's total) - 345.3us (R13, identical kernels).
    pool_cls_kernel<<<NB + POOL_ROWS + CONV_BLOCKS, 256, 0, stream>>>(
        pred, hs, f0, f1, f2, f3, ipw, inw, ow, l1w, l2w, c1w, c2w,
        pooled, tokG, biasW, wH, flagW);
    pool_cls_kernel<<<NB + POOL_ROWS + CONV_BLOCKS, 256, 0, stream>>>(
        pred, hs, f0, f1, f2, f3, ipw, inw, ow, l1w, l2w, c1w, c2w,
        pooled, tokG, biasW, wH, flagW);
    xform_kernel<<<4 * NB, 512, 0, stream>>>(
        pooled, tokG, biasW, wH, ipb, inb, ob, l1b, l2b,
        ln1w, ln1b, ln2w, ln2b, c1b, c2b,
        aoW, resW, h1W, hW, flagW, (float*)d_out);
}